// Round 2
// baseline (1834.415 us; speedup 1.0000x reference)
//
#include <hip/hip_runtime.h>
#include <math.h>

#define EMBED 1024
#define HEADS 16
#define HD 64
#define BATCH 4
#define TSEQ 4096
#define BH (BATCH * HEADS)

__device__ __forceinline__ float elu1(float v) {
    return v > 0.f ? v + 1.f : __expf(v);
}

__device__ __forceinline__ ushort f2bf(float f) {
    union { float f; unsigned u; } c; c.f = f;
    unsigned u = c.u + 0x7FFFu + ((c.u >> 16) & 1u);   // RNE
    return (ushort)(u >> 16);
}

__device__ __forceinline__ float bf2f(ushort u) {
    union { unsigned u; float f; } c; c.u = ((unsigned)u) << 16;
    return c.f;
}

__global__ void zero_kernel(float* __restrict__ p, int n) {
    int i = blockIdx.x * blockDim.x + threadIdx.x;
    if (i < n) p[i] = 0.f;
}

// ---------------------------------------------------------------------------
// fused_kv: per (b,h, t-chunk of 256 rows):
//   k = elu1(x @ Wk_h^T + bk_h), v = x @ Wv_h^T + bv_h  (computed on the fly)
//   kv[d][e] += sum_t k[t][d] v[t][e];  ksum[d] += sum_t k[t][d]
// 256 threads; projection tile 64 rows x 128 cols (k|v), BK=16.
// ---------------------------------------------------------------------------
__global__ __launch_bounds__(256) void fused_kv(
    const float* __restrict__ x,
    const float* __restrict__ Wk, const float* __restrict__ bk,
    const float* __restrict__ Wv, const float* __restrict__ bv,
    float* __restrict__ kvg, float* __restrict__ ksg)
{
    __shared__ float As[16][68];    // x tile   [k][t-row]
    __shared__ float Bs[16][132];   // Wk|Wv    [k][col: 0..63 k, 64..127 v]
    __shared__ float kt[64][68];    // k tile   [t][d]
    __shared__ float vt[64][68];    // v tile   [t][e]

    const int bh = blockIdx.x;
    const int b = bh / HEADS, h = bh % HEADS;
    const int tchunk = blockIdx.y * 256;

    const int tid = threadIdx.x;
    const int r0 = (tid >> 4) << 2;   // 0..60 : t-rows (and kv d-rows)
    const int c0 = (tid & 15) << 2;   // 0..60 : head cols (and kv e-cols)
    const int mL = tid >> 2;          // 0..63 loader row
    const int kL = (tid & 3) << 2;    // 0,4,8,12 loader k

    const float* Wkh = Wk + (size_t)h * HD * EMBED;
    const float* Wvh = Wv + (size_t)h * HD * EMBED;

    float bkc[4], bvc[4];
    #pragma unroll
    for (int j = 0; j < 4; ++j) {
        bkc[j] = bk[h * HD + c0 + j];
        bvc[j] = bv[h * HD + c0 + j];
    }

    float kvacc[4][4] = {};
    float ksacc = 0.f;

    for (int ss = 0; ss < 4; ++ss) {
        const size_t xrow = (size_t)b * TSEQ + tchunk + ss * 64;
        float ak[4][4] = {}, av[4][4] = {};

        for (int k0 = 0; k0 < EMBED; k0 += 16) {
            float4 xa  = *reinterpret_cast<const float4*>(&x[(xrow + mL) * EMBED + k0 + kL]);
            float4 wk4 = *reinterpret_cast<const float4*>(&Wkh[(size_t)mL * EMBED + k0 + kL]);
            float4 wv4 = *reinterpret_cast<const float4*>(&Wvh[(size_t)mL * EMBED + k0 + kL]);
            As[kL + 0][mL] = xa.x;  As[kL + 1][mL] = xa.y;
            As[kL + 2][mL] = xa.z;  As[kL + 3][mL] = xa.w;
            Bs[kL + 0][mL] = wk4.x; Bs[kL + 1][mL] = wk4.y;
            Bs[kL + 2][mL] = wk4.z; Bs[kL + 3][mL] = wk4.w;
            Bs[kL + 0][mL + 64] = wv4.x; Bs[kL + 1][mL + 64] = wv4.y;
            Bs[kL + 2][mL + 64] = wv4.z; Bs[kL + 3][mL + 64] = wv4.w;
            __syncthreads();
            #pragma unroll
            for (int kk = 0; kk < 16; ++kk) {
                float4 a4  = *reinterpret_cast<const float4*>(&As[kk][r0]);
                float4 b4  = *reinterpret_cast<const float4*>(&Bs[kk][c0]);
                float4 b4v = *reinterpret_cast<const float4*>(&Bs[kk][c0 + 64]);
                const float aa[4] = {a4.x, a4.y, a4.z, a4.w};
                const float kkv[4] = {b4.x, b4.y, b4.z, b4.w};
                const float vvv[4] = {b4v.x, b4v.y, b4v.z, b4v.w};
                #pragma unroll
                for (int i = 0; i < 4; ++i)
                    #pragma unroll
                    for (int j = 0; j < 4; ++j) {
                        ak[i][j] += aa[i] * kkv[j];
                        av[i][j] += aa[i] * vvv[j];
                    }
            }
            __syncthreads();
        }

        // epilogue: bias (+ elu1 for k) -> LDS tiles
        #pragma unroll
        for (int i = 0; i < 4; ++i) {
            float4 kw, vw;
            kw.x = elu1(ak[i][0] + bkc[0]); kw.y = elu1(ak[i][1] + bkc[1]);
            kw.z = elu1(ak[i][2] + bkc[2]); kw.w = elu1(ak[i][3] + bkc[3]);
            vw.x = av[i][0] + bvc[0]; vw.y = av[i][1] + bvc[1];
            vw.z = av[i][2] + bvc[2]; vw.w = av[i][3] + bvc[3];
            *reinterpret_cast<float4*>(&kt[r0 + i][c0]) = kw;
            *reinterpret_cast<float4*>(&vt[r0 + i][c0]) = vw;
        }
        __syncthreads();

        // kv outer-product accumulation over the 64 t-rows
        #pragma unroll 8
        for (int tt = 0; tt < 64; ++tt) {
            float4 ka = *reinterpret_cast<const float4*>(&kt[tt][r0]);
            float4 va = *reinterpret_cast<const float4*>(&vt[tt][c0]);
            const float kk4[4] = {ka.x, ka.y, ka.z, ka.w};
            const float vv4[4] = {va.x, va.y, va.z, va.w};
            #pragma unroll
            for (int i = 0; i < 4; ++i)
                #pragma unroll
                for (int j = 0; j < 4; ++j)
                    kvacc[i][j] += kk4[i] * vv4[j];
        }
        if (tid < 64) {
            #pragma unroll 8
            for (int tt = 0; tt < 64; ++tt) ksacc += kt[tt][tid];
        }
        __syncthreads();
    }

    #pragma unroll
    for (int i = 0; i < 4; ++i)
        #pragma unroll
        for (int j = 0; j < 4; ++j)
            atomicAdd(&kvg[(size_t)bh * (HD * HD) + (size_t)(r0 + i) * HD + c0 + j],
                      kvacc[i][j]);
    if (tid < 64) atomicAdd(&ksg[bh * HD + tid], ksacc);
}

// ---------------------------------------------------------------------------
// fused_y: per (b,h, 64 t-rows):
//   q = elu1(x @ Wq_h^T + bq_h); z = 1/(q . ksum + 1e-6); y = (q @ kv) * z
// y stored bf16 in [B,T,C] layout.
// ---------------------------------------------------------------------------
__global__ __launch_bounds__(256) void fused_y(
    const float* __restrict__ x,
    const float* __restrict__ Wq, const float* __restrict__ bq,
    const float* __restrict__ kvg, const float* __restrict__ ksg,
    ushort* __restrict__ y)
{
    __shared__ float As[16][68];
    __shared__ float Bs[16][68];
    __shared__ float qs[64][68];
    __shared__ float kvs[64][64];
    __shared__ float kss[64];
    __shared__ float zs[64];

    const int bh = blockIdx.x;
    const int b = bh / HEADS, h = bh % HEADS;
    const int t0 = blockIdx.y * 64;

    const int tid = threadIdx.x;
    const int r0 = (tid >> 4) << 2;
    const int c0 = (tid & 15) << 2;
    const int mL = tid >> 2;
    const int kL = (tid & 3) << 2;

    const float* Wqh = Wq + (size_t)h * HD * EMBED;

    // stage kv / ksum (reads complete before first use via loop barriers)
    #pragma unroll
    for (int idx = tid * 4; idx < HD * HD; idx += 1024)
        *reinterpret_cast<float4*>(&kvs[0][0] + idx) =
            *reinterpret_cast<const float4*>(&kvg[(size_t)bh * (HD * HD) + idx]);
    if (tid < 64) kss[tid] = ksg[bh * HD + tid];

    float acc[4][4] = {};
    const size_t xrow = (size_t)b * TSEQ + t0;

    for (int k0 = 0; k0 < EMBED; k0 += 16) {
        float4 xa  = *reinterpret_cast<const float4*>(&x[(xrow + mL) * EMBED + k0 + kL]);
        float4 wq4 = *reinterpret_cast<const float4*>(&Wqh[(size_t)mL * EMBED + k0 + kL]);
        As[kL + 0][mL] = xa.x;  As[kL + 1][mL] = xa.y;
        As[kL + 2][mL] = xa.z;  As[kL + 3][mL] = xa.w;
        Bs[kL + 0][mL] = wq4.x; Bs[kL + 1][mL] = wq4.y;
        Bs[kL + 2][mL] = wq4.z; Bs[kL + 3][mL] = wq4.w;
        __syncthreads();
        #pragma unroll
        for (int kk = 0; kk < 16; ++kk) {
            float4 a4 = *reinterpret_cast<const float4*>(&As[kk][r0]);
            float4 b4 = *reinterpret_cast<const float4*>(&Bs[kk][c0]);
            const float aa[4] = {a4.x, a4.y, a4.z, a4.w};
            const float bb[4] = {b4.x, b4.y, b4.z, b4.w};
            #pragma unroll
            for (int i = 0; i < 4; ++i)
                #pragma unroll
                for (int j = 0; j < 4; ++j)
                    acc[i][j] += aa[i] * bb[j];
        }
        __syncthreads();
    }

    // q epilogue
    float bqc[4];
    #pragma unroll
    for (int j = 0; j < 4; ++j) bqc[j] = bq[h * HD + c0 + j];
    #pragma unroll
    for (int i = 0; i < 4; ++i) {
        float4 qw;
        qw.x = elu1(acc[i][0] + bqc[0]); qw.y = elu1(acc[i][1] + bqc[1]);
        qw.z = elu1(acc[i][2] + bqc[2]); qw.w = elu1(acc[i][3] + bqc[3]);
        *reinterpret_cast<float4*>(&qs[r0 + i][c0]) = qw;
    }
    __syncthreads();

    // normalizers
    if (tid < 64) {
        float den = 0.f;
        #pragma unroll 8
        for (int d = 0; d < HD; ++d) den += qs[tid][d] * kss[d];
        zs[tid] = 1.f / (den + 1e-6f);
    }
    __syncthreads();

    // y = q @ kv
    float yacc[4][4] = {};
    #pragma unroll 8
    for (int d = 0; d < HD; ++d) {
        float4 kv4 = *reinterpret_cast<const float4*>(&kvs[d][c0]);
        const float qa[4] = {qs[r0 + 0][d], qs[r0 + 1][d], qs[r0 + 2][d], qs[r0 + 3][d]};
        const float kb[4] = {kv4.x, kv4.y, kv4.z, kv4.w};
        #pragma unroll
        for (int i = 0; i < 4; ++i)
            #pragma unroll
            for (int j = 0; j < 4; ++j)
                yacc[i][j] += qa[i] * kb[j];
    }

    #pragma unroll
    for (int i = 0; i < 4; ++i) {
        float z = zs[r0 + i];
        uint2 w;
        w.x = (unsigned)f2bf(yacc[i][0] * z) | ((unsigned)f2bf(yacc[i][1] * z) << 16);
        w.y = (unsigned)f2bf(yacc[i][2] * z) | ((unsigned)f2bf(yacc[i][3] * z) << 16);
        *reinterpret_cast<uint2*>(&y[(xrow + r0 + i) * EMBED + h * HD + c0]) = w;
    }
}

// ---------------------------------------------------------------------------
// final projection: out[M,N] = Y[M,K](bf16) @ Wc[N,K]^T + bc, fp32 out
// ---------------------------------------------------------------------------
__global__ __launch_bounds__(256) void gemm_yc(
    const ushort* __restrict__ Y, const float* __restrict__ W,
    const float* __restrict__ bias, float* __restrict__ out)
{
    __shared__ float As[16][68];
    __shared__ float Bs[16][68];

    const int bm = blockIdx.x * 64;
    const int bn = blockIdx.y * 64;
    const int tid = threadIdx.x;
    const int r0 = (tid >> 4) << 2;
    const int c0 = (tid & 15) << 2;
    const int mL = tid >> 2;
    const int kL = (tid & 3) << 2;

    float acc[4][4] = {};

    for (int k0 = 0; k0 < EMBED; k0 += 16) {
        ushort4 ya = *reinterpret_cast<const ushort4*>(&Y[(size_t)(bm + mL) * EMBED + k0 + kL]);
        float4 wb  = *reinterpret_cast<const float4*>(&W[(size_t)(bn + mL) * EMBED + k0 + kL]);
        As[kL + 0][mL] = bf2f(ya.x); As[kL + 1][mL] = bf2f(ya.y);
        As[kL + 2][mL] = bf2f(ya.z); As[kL + 3][mL] = bf2f(ya.w);
        Bs[kL + 0][mL] = wb.x; Bs[kL + 1][mL] = wb.y;
        Bs[kL + 2][mL] = wb.z; Bs[kL + 3][mL] = wb.w;
        __syncthreads();
        #pragma unroll
        for (int kk = 0; kk < 16; ++kk) {
            float4 a4 = *reinterpret_cast<const float4*>(&As[kk][r0]);
            float4 b4 = *reinterpret_cast<const float4*>(&Bs[kk][c0]);
            const float aa[4] = {a4.x, a4.y, a4.z, a4.w};
            const float bb[4] = {b4.x, b4.y, b4.z, b4.w};
            #pragma unroll
            for (int i = 0; i < 4; ++i)
                #pragma unroll
                for (int j = 0; j < 4; ++j)
                    acc[i][j] += aa[i] * bb[j];
        }
        __syncthreads();
    }

    #pragma unroll
    for (int i = 0; i < 4; ++i) {
        float4 o;
        o.x = acc[i][0] + bias[bn + c0 + 0];
        o.y = acc[i][1] + bias[bn + c0 + 1];
        o.z = acc[i][2] + bias[bn + c0 + 2];
        o.w = acc[i][3] + bias[bn + c0 + 3];
        *reinterpret_cast<float4*>(&out[(size_t)(bm + r0 + i) * EMBED + bn + c0]) = o;
    }
}

// ---------------------------------------------------------------------------
extern "C" void kernel_launch(void* const* d_in, const int* in_sizes, int n_in,
                              void* d_out, int out_size, void* d_ws, size_t ws_size,
                              hipStream_t stream) {
    (void)in_sizes; (void)n_in; (void)out_size; (void)ws_size;
    const float* x  = (const float*)d_in[0];
    const float* Wq = (const float*)d_in[1];
    const float* bq = (const float*)d_in[2];
    const float* Wk = (const float*)d_in[3];
    const float* bk = (const float*)d_in[4];
    const float* Wv = (const float*)d_in[5];
    const float* bv = (const float*)d_in[6];
    const float* Wc = (const float*)d_in[7];
    const float* bc = (const float*)d_in[8];
    float* out = (float*)d_out;

    // workspace layout (total ~34.6 MB):
    //   y (bf16)  : B*T*C ushorts = 33,554,432 B
    //   kv (fp32) : BH*64*64      =  1,048,576 B
    //   ks (fp32) : BH*64         =     16,384 B
    ushort* y_ws = (ushort*)d_ws;
    float* kv_ws = (float*)((char*)d_ws + (size_t)BATCH * TSEQ * EMBED * sizeof(ushort));
    float* ks_ws = kv_ws + (size_t)BH * HD * HD;

    const int nzero = BH * HD * HD + BH * HD;   // kv + ks contiguous
    zero_kernel<<<(nzero + 255) / 256, 256, 0, stream>>>(kv_ws, nzero);

    fused_kv<<<dim3(BH, TSEQ / 256), 256, 0, stream>>>(x, Wk, bk, Wv, bv, kv_ws, ks_ws);

    fused_y<<<dim3(BH, TSEQ / 64), 256, 0, stream>>>(x, Wq, bq, kv_ws, ks_ws, y_ws);

    gemm_yc<<<dim3((BATCH * TSEQ) / 64, EMBED / 64), 256, 0, stream>>>(y_ws, Wc, bc, out);
}

// Round 3
// 404.204 us; speedup vs baseline: 4.5383x; 4.5383x over previous
//
#include <hip/hip_runtime.h>
#include <math.h>

#define EMBED 1024
#define HEADS 16
#define HD 64
#define BATCH 4
#define TSEQ 4096
#define BH (BATCH * HEADS)

typedef _Float16 f16;
typedef __attribute__((ext_vector_type(4))) _Float16 f16x4;
typedef __attribute__((ext_vector_type(8))) _Float16 f16x8;
typedef __attribute__((ext_vector_type(4))) float f32x4;

__device__ __forceinline__ float elu1(float v) {
    return v > 0.f ? v + 1.f : __expf(v);
}

// XOR-swizzled element offset inside a [rows][cols] f16 tile (cols = 64 or 128).
// 8-element (16B) granules; granule ^= (row & 7). col may be any element index.
__device__ __forceinline__ int swzc(int row, int col, int cols) {
    int g = (col >> 3) ^ (row & 7);
    return row * cols + (g << 3) + (col & 7);
}

// load an MFMA fragment (8 contiguous k-elements) from a swizzled tile
__device__ __forceinline__ f16x8 fragld(const f16* t, int row, int k, int cols) {
    return *(const f16x8*)&t[swzc(row, k, cols)];
}

__device__ __forceinline__ f32x4 mfma16(f16x8 a, f16x8 b, f32x4 c) {
    return __builtin_amdgcn_mfma_f32_16x16x32_f16(a, b, c, 0, 0, 0);
}

__global__ void zero_kernel(float* __restrict__ p, int n) {
    int i = blockIdx.x * blockDim.x + threadIdx.x;
    if (i < n) p[i] = 0.f;
}

// ---------------------------------------------------------------------------
// fused_kv: grid (BH, 8). Block processes 4 tiles of 128 t-rows:
//   C[128t x 128c] = x @ [Wk_h ; Wv_h]^T  (fp16 MFMA, fp32 acc)
//   k = elu1(C[:,0:64]+bk)  -> kT[64][128] (f16, swizzled)
//   v = C[:,64:128]+bv      -> vT[64][128]
//   vk[e][d] += v^T k  (MFMA over t);  ksum[d] += sum_t k[t][d]
// ---------------------------------------------------------------------------
__global__ __launch_bounds__(256) void fused_kv(
    const float* __restrict__ x,
    const float* __restrict__ Wk, const float* __restrict__ bk,
    const float* __restrict__ Wv, const float* __restrict__ bv,
    float* __restrict__ vkg, float* __restrict__ ksg)
{
    __shared__ __align__(16) f16 As[128 * 64];
    __shared__ __align__(16) f16 Bs[128 * 64];
    __shared__ __align__(16) f16 kT[64 * 128];
    __shared__ __align__(16) f16 vT[64 * 128];

    const int bh = blockIdx.x;
    const int b = bh >> 4, h = bh & 15;
    const int tid = threadIdx.x;
    const int lane = tid & 63;
    const int w = tid >> 6;
    const int wr = w >> 1, wc = w & 1;
    const int l15 = lane & 15, l4 = lane >> 4;

    const float* Wkh = Wk + (size_t)h * HD * EMBED;
    const float* Wvh = Wv + (size_t)h * HD * EMBED;
    const float* biasp = wc ? (bv + h * HD) : (bk + h * HD);

    f32x4 kvacc[4];
    #pragma unroll
    for (int j = 0; j < 4; ++j) kvacc[j] = (f32x4){0.f, 0.f, 0.f, 0.f};
    float ksacc = 0.f;

    for (int ss = 0; ss < 4; ++ss) {
        const int trow0 = b * TSEQ + blockIdx.y * 512 + ss * 128;

        f32x4 acc[4][4];
        #pragma unroll
        for (int i = 0; i < 4; ++i)
            #pragma unroll
            for (int j = 0; j < 4; ++j) acc[i][j] = (f32x4){0.f, 0.f, 0.f, 0.f};

        for (int k0 = 0; k0 < EMBED; k0 += 64) {
            #pragma unroll
            for (int c = 0; c < 8; ++c) {
                int idx = tid + c * 256;
                int row = idx >> 4, col = (idx & 15) << 2;
                float4 f = *(const float4*)&x[(size_t)(trow0 + row) * EMBED + k0 + col];
                f16x4 hv = {(f16)f.x, (f16)f.y, (f16)f.z, (f16)f.w};
                *(f16x4*)&As[swzc(row, col, 64)] = hv;
                const float* wsrc = (row < 64) ? (Wkh + (size_t)row * EMBED)
                                               : (Wvh + (size_t)(row - 64) * EMBED);
                float4 g = *(const float4*)&wsrc[k0 + col];
                f16x4 hw = {(f16)g.x, (f16)g.y, (f16)g.z, (f16)g.w};
                *(f16x4*)&Bs[swzc(row, col, 64)] = hw;
            }
            __syncthreads();
            #pragma unroll
            for (int kk = 0; kk < 64; kk += 32) {
                f16x8 af[4], bf[4];
                #pragma unroll
                for (int i = 0; i < 4; ++i)
                    af[i] = fragld(As, wr * 64 + i * 16 + l15, kk + l4 * 8, 64);
                #pragma unroll
                for (int j = 0; j < 4; ++j)
                    bf[j] = fragld(Bs, wc * 64 + j * 16 + l15, kk + l4 * 8, 64);
                #pragma unroll
                for (int i = 0; i < 4; ++i)
                    #pragma unroll
                    for (int j = 0; j < 4; ++j)
                        acc[i][j] = mfma16(af[i], bf[j], acc[i][j]);
            }
            __syncthreads();
        }

        // epilogue: write k^T (elu1+bias) / v^T (bias) as f16, swizzled, 8B stores
        f16* dst = wc ? vT : kT;
        #pragma unroll
        for (int j = 0; j < 4; ++j) {
            int d = j * 16 + l15;
            float bj = biasp[d];
            #pragma unroll
            for (int i = 0; i < 4; ++i) {
                int t = wr * 64 + i * 16 + l4 * 4;
                f16x4 hv;
                #pragma unroll
                for (int r = 0; r < 4; ++r) {
                    float v = acc[i][j][r] + bj;
                    if (wc == 0) v = elu1(v);
                    hv[r] = (f16)v;
                }
                *(f16x4*)&dst[swzc(d, t, 128)] = hv;
            }
        }
        __syncthreads();

        // vk[e][d] += sum_t v[t][e] k[t][d] ; wave w owns e-range 16w..16w+15
        #pragma unroll
        for (int kk = 0; kk < 128; kk += 32) {
            f16x8 a = fragld(vT, 16 * w + l15, kk + l4 * 8, 128);
            #pragma unroll
            for (int j = 0; j < 4; ++j) {
                f16x8 bfr = fragld(kT, j * 16 + l15, kk + l4 * 8, 128);
                kvacc[j] = mfma16(a, bfr, kvacc[j]);
            }
        }
        // ksum partial: thread (d = tid&63, quarter = tid>>6)
        {
            int d = tid & 63, qq = tid >> 6;
            #pragma unroll
            for (int t8 = 0; t8 < 32; t8 += 8) {
                f16x8 kv8 = fragld(kT, d, qq * 32 + t8, 128);
                #pragma unroll
                for (int e = 0; e < 8; ++e) ksacc += (float)kv8[e];
            }
        }
        __syncthreads();
    }

    #pragma unroll
    for (int j = 0; j < 4; ++j)
        #pragma unroll
        for (int r = 0; r < 4; ++r)
            atomicAdd(&vkg[(size_t)bh * 4096 +
                           (size_t)(16 * w + l4 * 4 + r) * HD + j * 16 + l15],
                      kvacc[j][r]);
    atomicAdd(&ksg[bh * HD + (tid & 63)], ksacc);
}

// ---------------------------------------------------------------------------
// fused_y: grid (M/128, HEADS). Block: q = elu1(x @ Wq_h^T + bq) [128x64],
// z[t] = 1/(q . ksum + 1e-6), y^T[e][t] = sum_d vk[e][d] q[t][d], y *= z.
// y stored f16 in [B,T,C].
// ---------------------------------------------------------------------------
__global__ __launch_bounds__(256) void fused_y(
    const float* __restrict__ x,
    const float* __restrict__ Wq, const float* __restrict__ bq,
    const float* __restrict__ vkg, const float* __restrict__ ksg,
    f16* __restrict__ y)
{
    __shared__ __align__(16) f16 As[128 * 64];
    __shared__ __align__(16) f16 Bs[64 * 64];
    __shared__ __align__(16) f16 qs[128 * 64];
    __shared__ __align__(16) f16 kvs[64 * 64];
    __shared__ __align__(16) f16 ylds[128 * 64];
    __shared__ float kss[64];
    __shared__ float zs[128];

    const int tid = threadIdx.x;
    const int lane = tid & 63, w = tid >> 6;
    const int wr = w >> 1, wc = w & 1;
    const int l15 = lane & 15, l4 = lane >> 4;
    const int h = blockIdx.y;
    const int trow0 = blockIdx.x * 128;
    const int bh = (trow0 >> 12) * HEADS + h;
    const float* Wqh = Wq + (size_t)h * HD * EMBED;

    // stage vk (fp32 -> f16, swizzled) and ksum
    #pragma unroll
    for (int c = 0; c < 4; ++c) {
        int idx = tid + c * 256;
        int row = idx >> 4, col = (idx & 15) << 2;
        float4 f = *(const float4*)&vkg[(size_t)bh * 4096 + row * HD + col];
        f16x4 hv = {(f16)f.x, (f16)f.y, (f16)f.z, (f16)f.w};
        *(f16x4*)&kvs[swzc(row, col, 64)] = hv;
    }
    if (tid < 64) kss[tid] = ksg[bh * HD + tid];

    f32x4 qacc[4][2];
    #pragma unroll
    for (int i = 0; i < 4; ++i)
        #pragma unroll
        for (int j = 0; j < 2; ++j) qacc[i][j] = (f32x4){0.f, 0.f, 0.f, 0.f};

    for (int k0 = 0; k0 < EMBED; k0 += 64) {
        #pragma unroll
        for (int c = 0; c < 8; ++c) {
            int idx = tid + c * 256;
            int row = idx >> 4, col = (idx & 15) << 2;
            float4 f = *(const float4*)&x[(size_t)(trow0 + row) * EMBED + k0 + col];
            f16x4 hv = {(f16)f.x, (f16)f.y, (f16)f.z, (f16)f.w};
            *(f16x4*)&As[swzc(row, col, 64)] = hv;
        }
        #pragma unroll
        for (int c = 0; c < 4; ++c) {
            int idx = tid + c * 256;
            int row = idx >> 4, col = (idx & 15) << 2;
            float4 f = *(const float4*)&Wqh[(size_t)row * EMBED + k0 + col];
            f16x4 hv = {(f16)f.x, (f16)f.y, (f16)f.z, (f16)f.w};
            *(f16x4*)&Bs[swzc(row, col, 64)] = hv;
        }
        __syncthreads();
        #pragma unroll
        for (int kk = 0; kk < 64; kk += 32) {
            f16x8 af[4], bf[2];
            #pragma unroll
            for (int i = 0; i < 4; ++i)
                af[i] = fragld(As, wr * 64 + i * 16 + l15, kk + l4 * 8, 64);
            #pragma unroll
            for (int j = 0; j < 2; ++j)
                bf[j] = fragld(Bs, wc * 32 + j * 16 + l15, kk + l4 * 8, 64);
            #pragma unroll
            for (int i = 0; i < 4; ++i)
                #pragma unroll
                for (int j = 0; j < 2; ++j)
                    qacc[i][j] = mfma16(af[i], bf[j], qacc[i][j]);
        }
        __syncthreads();
    }

    // q epilogue -> qs[t][c] (scalar f16, swizzled)
    #pragma unroll
    for (int j = 0; j < 2; ++j) {
        int cc = wc * 32 + j * 16 + l15;
        float bj = bq[h * HD + cc];
        #pragma unroll
        for (int i = 0; i < 4; ++i) {
            #pragma unroll
            for (int r = 0; r < 4; ++r) {
                int t = wr * 64 + i * 16 + l4 * 4 + r;
                qs[swzc(t, cc, 64)] = (f16)elu1(qacc[i][j][r] + bj);
            }
        }
    }
    __syncthreads();

    // z[t] = 1/(q[t,:] . ksum + 1e-6)
    {
        int t = tid >> 1, dh = (tid & 1) * 32;
        float s = 0.f;
        #pragma unroll
        for (int d8 = 0; d8 < 32; d8 += 8) {
            f16x8 qv = fragld(qs, t, dh + d8, 64);
            #pragma unroll
            for (int e = 0; e < 8; ++e) s += (float)qv[e] * kss[dh + d8 + e];
        }
        s += __shfl_xor(s, 1);
        if ((tid & 1) == 0) zs[t] = 1.f / (s + 1e-6f);
    }
    __syncthreads();

    // y^T[e][t] = sum_d vk[e][d] q[t][d]; wave w owns e-range 16w..16w+15
    f32x4 yacc[8];
    #pragma unroll
    for (int jn = 0; jn < 8; ++jn) yacc[jn] = (f32x4){0.f, 0.f, 0.f, 0.f};
    #pragma unroll
    for (int kk = 0; kk < 64; kk += 32) {
        f16x8 a = fragld(kvs, 16 * w + l15, kk + l4 * 8, 64);
        #pragma unroll
        for (int jn = 0; jn < 8; ++jn) {
            f16x8 bq8 = fragld(qs, jn * 16 + l15, kk + l4 * 8, 64);
            yacc[jn] = mfma16(a, bq8, yacc[jn]);
        }
    }
    // scale by z, write ylds[t][e]
    #pragma unroll
    for (int jn = 0; jn < 8; ++jn) {
        int t = jn * 16 + l15;
        float z = zs[t];
        int e0 = 16 * w + l4 * 4;
        f16x4 hv;
        #pragma unroll
        for (int r = 0; r < 4; ++r) hv[r] = (f16)(yacc[jn][r] * z);
        *(f16x4*)&ylds[swzc(t, e0, 64)] = hv;
    }
    __syncthreads();

    // coalesced-ish store of y tile
    {
        int row = tid >> 1, eh = (tid & 1) * 32;
        size_t gb = (size_t)(trow0 + row) * EMBED + h * HD + eh;
        #pragma unroll
        for (int c8 = 0; c8 < 32; c8 += 8) {
            f16x8 v = fragld(ylds, row, eh + c8, 64);
            *(f16x8*)&y[gb + c8] = v;
        }
    }
}

// ---------------------------------------------------------------------------
// gemm_out: out[M,N] = y[M,K](f16) @ Wc[N,K]^T + bc, fp32 out. 128x128 tiles.
// ---------------------------------------------------------------------------
__global__ __launch_bounds__(256) void gemm_out(
    const f16* __restrict__ y, const float* __restrict__ Wc,
    const float* __restrict__ bc, float* __restrict__ out)
{
    __shared__ __align__(16) f16 As[128 * 64];
    __shared__ __align__(16) f16 Bs[128 * 64];

    const int tid = threadIdx.x;
    const int lane = tid & 63, w = tid >> 6;
    const int wr = w >> 1, wc4 = w & 1;
    const int l15 = lane & 15, l4 = lane >> 4;
    const int mb = blockIdx.x * 128, nb = blockIdx.y * 128;

    f32x4 acc[4][4];
    #pragma unroll
    for (int i = 0; i < 4; ++i)
        #pragma unroll
        for (int j = 0; j < 4; ++j) acc[i][j] = (f32x4){0.f, 0.f, 0.f, 0.f};

    for (int k0 = 0; k0 < EMBED; k0 += 64) {
        #pragma unroll
        for (int c = 0; c < 4; ++c) {      // y is already f16: 16B chunks
            int idx = tid + c * 256;
            int row = idx >> 3, col = (idx & 7) << 3;
            f16x8 v = *(const f16x8*)&y[(size_t)(mb + row) * EMBED + k0 + col];
            *(f16x8*)&As[swzc(row, col, 64)] = v;
        }
        #pragma unroll
        for (int c = 0; c < 8; ++c) {      // Wc fp32 -> f16
            int idx = tid + c * 256;
            int row = idx >> 4, col = (idx & 15) << 2;
            float4 f = *(const float4*)&Wc[(size_t)(nb + row) * EMBED + k0 + col];
            f16x4 hv = {(f16)f.x, (f16)f.y, (f16)f.z, (f16)f.w};
            *(f16x4*)&Bs[swzc(row, col, 64)] = hv;
        }
        __syncthreads();
        #pragma unroll
        for (int kk = 0; kk < 64; kk += 32) {
            f16x8 af[4], bf[4];
            #pragma unroll
            for (int i = 0; i < 4; ++i)
                af[i] = fragld(As, wr * 64 + i * 16 + l15, kk + l4 * 8, 64);
            #pragma unroll
            for (int j = 0; j < 4; ++j)
                bf[j] = fragld(Bs, wc4 * 64 + j * 16 + l15, kk + l4 * 8, 64);
            #pragma unroll
            for (int i = 0; i < 4; ++i)
                #pragma unroll
                for (int j = 0; j < 4; ++j)
                    acc[i][j] = mfma16(af[i], bf[j], acc[i][j]);
        }
        __syncthreads();
    }

    #pragma unroll
    for (int j = 0; j < 4; ++j) {
        int n = nb + wc4 * 64 + j * 16 + l15;
        float bj = bc[n];
        #pragma unroll
        for (int i = 0; i < 4; ++i) {
            #pragma unroll
            for (int r = 0; r < 4; ++r) {
                int m = mb + wr * 64 + i * 16 + l4 * 4 + r;
                out[(size_t)m * EMBED + n] = acc[i][j][r] + bj;
            }
        }
    }
}

// ---------------------------------------------------------------------------
extern "C" void kernel_launch(void* const* d_in, const int* in_sizes, int n_in,
                              void* d_out, int out_size, void* d_ws, size_t ws_size,
                              hipStream_t stream) {
    (void)in_sizes; (void)n_in; (void)out_size; (void)ws_size;
    const float* x  = (const float*)d_in[0];
    const float* Wq = (const float*)d_in[1];
    const float* bq = (const float*)d_in[2];
    const float* Wk = (const float*)d_in[3];
    const float* bk = (const float*)d_in[4];
    const float* Wv = (const float*)d_in[5];
    const float* bv = (const float*)d_in[6];
    const float* Wc = (const float*)d_in[7];
    const float* bc = (const float*)d_in[8];
    float* out = (float*)d_out;

    // workspace: y f16 (32MB) | vk fp32 (1MB) | ks fp32 (16KB)  => ~34.6MB
    f16* y_ws = (f16*)d_ws;
    float* vk_ws = (float*)((char*)d_ws + (size_t)BATCH * TSEQ * EMBED * sizeof(f16));
    float* ks_ws = vk_ws + (size_t)BH * HD * HD;

    const int nzero = BH * HD * HD + BH * HD;
    zero_kernel<<<(nzero + 255) / 256, 256, 0, stream>>>(vk_ws, nzero);

    fused_kv<<<dim3(BH, TSEQ / 512), 256, 0, stream>>>(x, Wk, bk, Wv, bv, vk_ws, ks_ws);

    fused_y<<<dim3((BATCH * TSEQ) / 128, HEADS), 256, 0, stream>>>(x, Wq, bq, vk_ws, ks_ws, y_ws);

    gemm_out<<<dim3((BATCH * TSEQ) / 128, EMBED / 128), 256, 0, stream>>>(y_ws, Wc, bc, out);
}

// Round 4
// 259.725 us; speedup vs baseline: 7.0629x; 1.5563x over previous
//
#include <hip/hip_runtime.h>
#include <math.h>

#define EMBED 1024
#define HEADS 16
#define HD 64
#define BATCH 4
#define TSEQ 4096
#define BH (BATCH * HEADS)
#define MROWS (BATCH * TSEQ)   // 16384

typedef _Float16 f16;
typedef __attribute__((ext_vector_type(4))) _Float16 f16x4;
typedef __attribute__((ext_vector_type(8))) _Float16 f16x8;
typedef __attribute__((ext_vector_type(4))) float f32x4;

__device__ __forceinline__ float elu1(float v) {
    return v > 0.f ? v + 1.f : __expf(v);
}

// XOR-swizzled element offset in a [rows][cols] f16 tile; 16B granules.
__device__ __forceinline__ int swzc(int row, int col, int cols) {
    int g = (col >> 3) ^ (row & 7);
    return row * cols + (g << 3) + (col & 7);
}

__device__ __forceinline__ f16x8 fragld(const f16* t, int row, int k, int cols) {
    return *(const f16x8*)&t[swzc(row, k, cols)];
}

__device__ __forceinline__ f32x4 mfma16(f16x8 a, f16x8 b, f32x4 c) {
    return __builtin_amdgcn_mfma_f32_16x16x32_f16(a, b, c, 0, 0, 0);
}

__global__ __launch_bounds__(256) void zero_kernel(float* __restrict__ p, int n) {
    int i = blockIdx.x * 256 + threadIdx.x;
    if (i < n) p[i] = 0.f;
}

// x fp32 -> f16, grid-stride-free exact cover: 16384 blocks x 256 thr x 4 elem
__global__ __launch_bounds__(256) void cvt_x(const float* __restrict__ x, f16* __restrict__ xh) {
    size_t i4 = (size_t)blockIdx.x * 256 + threadIdx.x;
    float4 f = *(const float4*)&x[i4 * 4];
    f16x4 h = {(f16)f.x, (f16)f.y, (f16)f.z, (f16)f.w};
    *(f16x4*)&xh[i4 * 4] = h;
}

// pack [Wq;Wk;Wv;Wc] -> Wall f16 [4096][1024], biases -> ball f32 [4096]
__global__ __launch_bounds__(256) void pack_w(
    const float* __restrict__ Wq, const float* __restrict__ Wk,
    const float* __restrict__ Wv, const float* __restrict__ Wc,
    const float* __restrict__ bq, const float* __restrict__ bk,
    const float* __restrict__ bv, const float* __restrict__ bc,
    f16* __restrict__ Wall, float* __restrict__ ball)
{
    int i4 = blockIdx.x * 256 + threadIdx.x;           // < 1048576
    int cls = i4 >> 18;
    const float* W = cls == 0 ? Wq : cls == 1 ? Wk : cls == 2 ? Wv : Wc;
    int off = (i4 & 0x3FFFF) * 4;
    float4 f = *(const float4*)&W[off];
    f16x4 h = {(f16)f.x, (f16)f.y, (f16)f.z, (f16)f.w};
    *(f16x4*)&Wall[(size_t)i4 * 4] = h;
    if (i4 < 4096) {
        int c2 = i4 >> 10;
        const float* bb = c2 == 0 ? bq : c2 == 1 ? bk : c2 == 2 ? bv : bc;
        ball[i4] = bb[i4 & 1023];
    }
}

// ---------------------------------------------------------------------------
// gemm_qkv: C[M=16384, N=3072] = xh @ Wall[0:3072]^T, f16 MFMA, fp32 acc.
// class = n/1024: 0=q (elu, row-major out), 1=k (elu, transposed out kT[d][t]),
// 2=v (no act, transposed out vT[d][t]).
// 128x128 tile, BK=64, 256 threads (2x2 waves, 64x64 each).
// ---------------------------------------------------------------------------
__global__ __launch_bounds__(256) void gemm_qkv(
    const f16* __restrict__ xh, const f16* __restrict__ Wall,
    const float* __restrict__ ball,
    f16* __restrict__ q, f16* __restrict__ kT, f16* __restrict__ vT)
{
    __shared__ __align__(16) f16 As[128 * 64];
    __shared__ __align__(16) f16 Bs[128 * 64];

    const int tid = threadIdx.x, lane = tid & 63, w = tid >> 6;
    const int wr = w >> 1, wc4 = w & 1, l15 = lane & 15, l4 = lane >> 4;
    const int m0 = blockIdx.x * 128;
    const int n0 = blockIdx.y * 128;
    const int cls = n0 >> 10;

    f32x4 acc[4][4];
    #pragma unroll
    for (int i = 0; i < 4; ++i)
        #pragma unroll
        for (int j = 0; j < 4; ++j) acc[i][j] = (f32x4){0.f, 0.f, 0.f, 0.f};

    for (int k0 = 0; k0 < EMBED; k0 += 64) {
        #pragma unroll
        for (int c = 0; c < 4; ++c) {
            int idx = tid + c * 256;
            int row = idx >> 3, col8 = (idx & 7) << 3;
            f16x8 va = *(const f16x8*)&xh[(size_t)(m0 + row) * EMBED + k0 + col8];
            *(f16x8*)&As[swzc(row, col8, 64)] = va;
            f16x8 vb = *(const f16x8*)&Wall[(size_t)(n0 + row) * EMBED + k0 + col8];
            *(f16x8*)&Bs[swzc(row, col8, 64)] = vb;
        }
        __syncthreads();
        #pragma unroll
        for (int kk = 0; kk < 64; kk += 32) {
            f16x8 af[4], bf[4];
            #pragma unroll
            for (int i = 0; i < 4; ++i)
                af[i] = fragld(As, wr * 64 + i * 16 + l15, kk + l4 * 8, 64);
            #pragma unroll
            for (int j = 0; j < 4; ++j)
                bf[j] = fragld(Bs, wc4 * 64 + j * 16 + l15, kk + l4 * 8, 64);
            #pragma unroll
            for (int i = 0; i < 4; ++i)
                #pragma unroll
                for (int j = 0; j < 4; ++j)
                    acc[i][j] = mfma16(af[i], bf[j], acc[i][j]);
        }
        __syncthreads();
    }

    if (cls == 0) {
        // q: elu1, row-major [t][c]
        #pragma unroll
        for (int j = 0; j < 4; ++j) {
            int c = n0 + wc4 * 64 + j * 16 + l15;
            float bj = ball[c];
            #pragma unroll
            for (int i = 0; i < 4; ++i) {
                #pragma unroll
                for (int r = 0; r < 4; ++r) {
                    int t = m0 + wr * 64 + i * 16 + l4 * 4 + r;
                    q[(size_t)t * EMBED + c] = (f16)elu1(acc[i][j][r] + bj);
                }
            }
        }
    } else {
        // k/v: transposed [d][t], f16x4 packs along t
        f16* dst = (cls == 1) ? kT : vT;
        const bool act = (cls == 1);
        #pragma unroll
        for (int j = 0; j < 4; ++j) {
            int n = n0 + wc4 * 64 + j * 16 + l15;
            int d = n & 1023;
            float bj = ball[n];
            #pragma unroll
            for (int i = 0; i < 4; ++i) {
                int t = m0 + wr * 64 + i * 16 + l4 * 4;
                f16x4 hv;
                #pragma unroll
                for (int r = 0; r < 4; ++r) {
                    float v = acc[i][j][r] + bj;
                    if (act) v = elu1(v);
                    hv[r] = (f16)v;
                }
                *(f16x4*)&dst[(size_t)d * MROWS + t] = hv;
            }
        }
    }
}

// ---------------------------------------------------------------------------
// kv_ksum: per (bh, 512-t chunk): kvg[e][d] += sum_t v[t,e] k[t,d] (MFMA),
// ksg[d] += sum_t k[t,d]. Inputs kT,vT are [1024 d][16384 t] f16.
// ---------------------------------------------------------------------------
__global__ __launch_bounds__(256) void kv_ksum(
    const f16* __restrict__ kT, const f16* __restrict__ vT,
    float* __restrict__ kvg, float* __restrict__ ksg)
{
    __shared__ __align__(16) f16 kl[64 * 128];
    __shared__ __align__(16) f16 vl[64 * 128];

    const int bh = blockIdx.x, b = bh >> 4, h = bh & 15;
    const int tid = threadIdx.x, lane = tid & 63, w = tid >> 6;
    const int l15 = lane & 15, l4 = lane >> 4;
    const int tbase = b * TSEQ + blockIdx.y * 512;

    f32x4 kvacc[4];
    #pragma unroll
    for (int j = 0; j < 4; ++j) kvacc[j] = (f32x4){0.f, 0.f, 0.f, 0.f};
    float ksacc = 0.f;

    for (int ss = 0; ss < 4; ++ss) {
        const int tg = tbase + ss * 128;
        #pragma unroll
        for (int c = 0; c < 4; ++c) {
            int idx = tid + c * 256;
            int row = idx >> 4, t8 = (idx & 15) << 3;
            f16x8 a = *(const f16x8*)&kT[(size_t)(h * 64 + row) * MROWS + tg + t8];
            *(f16x8*)&kl[swzc(row, t8, 128)] = a;
            f16x8 bb = *(const f16x8*)&vT[(size_t)(h * 64 + row) * MROWS + tg + t8];
            *(f16x8*)&vl[swzc(row, t8, 128)] = bb;
        }
        __syncthreads();
        #pragma unroll
        for (int kk = 0; kk < 128; kk += 32) {
            f16x8 a = fragld(vl, 16 * w + l15, kk + l4 * 8, 128);
            #pragma unroll
            for (int j = 0; j < 4; ++j) {
                f16x8 bfr = fragld(kl, j * 16 + l15, kk + l4 * 8, 128);
                kvacc[j] = mfma16(a, bfr, kvacc[j]);
            }
        }
        {
            int d = tid & 63, qq = tid >> 6;
            #pragma unroll
            for (int t8 = 0; t8 < 32; t8 += 8) {
                f16x8 kv8 = fragld(kl, d, qq * 32 + t8, 128);
                #pragma unroll
                for (int e = 0; e < 8; ++e) ksacc += (float)kv8[e];
            }
        }
        __syncthreads();
    }

    #pragma unroll
    for (int j = 0; j < 4; ++j)
        #pragma unroll
        for (int r = 0; r < 4; ++r)
            atomicAdd(&kvg[(size_t)bh * 4096 +
                           (size_t)(16 * w + l4 * 4 + r) * HD + j * 16 + l15],
                      kvacc[j][r]);
    atomicAdd(&ksg[bh * HD + (tid & 63)], ksacc);
}

// ---------------------------------------------------------------------------
// y_kernel: per (bh, 128 t): z[t]=1/(q.ks+1e-6); y[t][e]=sum_d q[t,d]kv[d,e]*z
// kvg layout [e][d] == kv2[d][e]. y written in place over q's column block.
// ---------------------------------------------------------------------------
__global__ __launch_bounds__(256) void y_kernel(
    const f16* __restrict__ q, const float* __restrict__ kvg,
    const float* __restrict__ ksg, f16* __restrict__ y)
{
    __shared__ __align__(16) f16 qs[128 * 64];
    __shared__ __align__(16) f16 kvs[64 * 64];
    __shared__ __align__(16) f16 ylds[128 * 64];
    __shared__ float kss[64];
    __shared__ float zs[128];

    const int bh = blockIdx.x, b = bh >> 4, h = bh & 15;
    const int tid = threadIdx.x, lane = tid & 63, w = tid >> 6;
    const int l15 = lane & 15, l4 = lane >> 4;
    const int t0g = b * TSEQ + blockIdx.y * 128;

    // stage q tile [128][64]
    #pragma unroll
    for (int c = 0; c < 4; ++c) {
        int idx = tid + c * 256;
        int row = idx >> 3, col8 = (idx & 7) << 3;
        f16x8 v = *(const f16x8*)&q[(size_t)(t0g + row) * EMBED + h * 64 + col8];
        *(f16x8*)&qs[swzc(row, col8, 64)] = v;
    }
    // stage kv [64 e][64 d] fp32->f16
    #pragma unroll
    for (int c = 0; c < 4; ++c) {
        int idx = tid + c * 256;
        int e = idx >> 4, d4 = (idx & 15) << 2;
        float4 f = *(const float4*)&kvg[(size_t)bh * 4096 + e * 64 + d4];
        f16x4 hv = {(f16)f.x, (f16)f.y, (f16)f.z, (f16)f.w};
        *(f16x4*)&kvs[swzc(e, d4, 64)] = hv;
    }
    if (tid < 64) kss[tid] = ksg[bh * HD + tid];
    __syncthreads();

    // z
    {
        int t = tid >> 1, dh = (tid & 1) * 32;
        float s = 0.f;
        #pragma unroll
        for (int d8 = 0; d8 < 32; d8 += 8) {
            f16x8 qv = fragld(qs, t, dh + d8, 64);
            #pragma unroll
            for (int e = 0; e < 8; ++e) s += (float)qv[e] * kss[dh + d8 + e];
        }
        s += __shfl_xor(s, 1);
        if ((tid & 1) == 0) zs[t] = 1.f / (s + 1e-6f);
    }
    __syncthreads();

    // y^T[e][t]: A = kv rows e (wave w: e 16w..), B = q rows t (8 tiles)
    f32x4 yacc[8];
    #pragma unroll
    for (int jn = 0; jn < 8; ++jn) yacc[jn] = (f32x4){0.f, 0.f, 0.f, 0.f};
    #pragma unroll
    for (int kk = 0; kk < 64; kk += 32) {
        f16x8 a = fragld(kvs, 16 * w + l15, kk + l4 * 8, 64);
        #pragma unroll
        for (int jn = 0; jn < 8; ++jn) {
            f16x8 bq8 = fragld(qs, jn * 16 + l15, kk + l4 * 8, 64);
            yacc[jn] = mfma16(a, bq8, yacc[jn]);
        }
    }
    #pragma unroll
    for (int jn = 0; jn < 8; ++jn) {
        int t = jn * 16 + l15;
        float z = zs[t];
        int e0 = 16 * w + l4 * 4;
        f16x4 hv;
        #pragma unroll
        for (int r = 0; r < 4; ++r) hv[r] = (f16)(yacc[jn][r] * z);
        *(f16x4*)&ylds[swzc(t, e0, 64)] = hv;
    }
    __syncthreads();

    {
        int row = tid >> 1, eh = (tid & 1) * 32;
        size_t gb = (size_t)(t0g + row) * EMBED + h * 64 + eh;
        #pragma unroll
        for (int c8 = 0; c8 < 32; c8 += 8) {
            f16x8 v = fragld(ylds, row, eh + c8, 64);
            *(f16x8*)&y[gb + c8] = v;
        }
    }
}

// ---------------------------------------------------------------------------
// gemm_out: out[M,1024] = y @ Wc^T + bc (Wc = Wall rows 3072..4095), fp32 out
// ---------------------------------------------------------------------------
__global__ __launch_bounds__(256) void gemm_out(
    const f16* __restrict__ y, const f16* __restrict__ Wall,
    const float* __restrict__ ball, float* __restrict__ out)
{
    __shared__ __align__(16) f16 As[128 * 64];
    __shared__ __align__(16) f16 Bs[128 * 64];

    const int tid = threadIdx.x, lane = tid & 63, w = tid >> 6;
    const int wr = w >> 1, wc4 = w & 1, l15 = lane & 15, l4 = lane >> 4;
    const int m0 = blockIdx.x * 128;
    const int n0 = blockIdx.y * 128;

    f32x4 acc[4][4];
    #pragma unroll
    for (int i = 0; i < 4; ++i)
        #pragma unroll
        for (int j = 0; j < 4; ++j) acc[i][j] = (f32x4){0.f, 0.f, 0.f, 0.f};

    for (int k0 = 0; k0 < EMBED; k0 += 64) {
        #pragma unroll
        for (int c = 0; c < 4; ++c) {
            int idx = tid + c * 256;
            int row = idx >> 3, col8 = (idx & 7) << 3;
            f16x8 va = *(const f16x8*)&y[(size_t)(m0 + row) * EMBED + k0 + col8];
            *(f16x8*)&As[swzc(row, col8, 64)] = va;
            f16x8 vb = *(const f16x8*)&Wall[(size_t)(3072 + n0 + row) * EMBED + k0 + col8];
            *(f16x8*)&Bs[swzc(row, col8, 64)] = vb;
        }
        __syncthreads();
        #pragma unroll
        for (int kk = 0; kk < 64; kk += 32) {
            f16x8 af[4], bf[4];
            #pragma unroll
            for (int i = 0; i < 4; ++i)
                af[i] = fragld(As, wr * 64 + i * 16 + l15, kk + l4 * 8, 64);
            #pragma unroll
            for (int j = 0; j < 4; ++j)
                bf[j] = fragld(Bs, wc4 * 64 + j * 16 + l15, kk + l4 * 8, 64);
            #pragma unroll
            for (int i = 0; i < 4; ++i)
                #pragma unroll
                for (int j = 0; j < 4; ++j)
                    acc[i][j] = mfma16(af[i], bf[j], acc[i][j]);
        }
        __syncthreads();
    }

    #pragma unroll
    for (int j = 0; j < 4; ++j) {
        int n = n0 + wc4 * 64 + j * 16 + l15;
        float bj = ball[3072 + n];
        #pragma unroll
        for (int i = 0; i < 4; ++i) {
            #pragma unroll
            for (int r = 0; r < 4; ++r) {
                int m = m0 + wr * 64 + i * 16 + l4 * 4 + r;
                out[(size_t)m * EMBED + n] = acc[i][j][r] + bj;
            }
        }
    }
}

// ---------------------------------------------------------------------------
extern "C" void kernel_launch(void* const* d_in, const int* in_sizes, int n_in,
                              void* d_out, int out_size, void* d_ws, size_t ws_size,
                              hipStream_t stream) {
    (void)in_sizes; (void)n_in; (void)out_size; (void)ws_size;
    const float* x  = (const float*)d_in[0];
    const float* Wq = (const float*)d_in[1];
    const float* bq = (const float*)d_in[2];
    const float* Wk = (const float*)d_in[3];
    const float* bk = (const float*)d_in[4];
    const float* Wv = (const float*)d_in[5];
    const float* bv = (const float*)d_in[6];
    const float* Wc = (const float*)d_in[7];
    const float* bc = (const float*)d_in[8];
    float* out = (float*)d_out;

    // workspace layout (~137.1 MB):
    //   xh   f16 [16384][1024]  32MB @ 0
    //   q/y  f16 [16384][1024]  32MB @ 32MB   (y overwrites q in place)
    //   kT   f16 [1024][16384]  32MB @ 64MB
    //   vT   f16 [1024][16384]  32MB @ 96MB
    //   Wall f16 [4096][1024]    8MB @ 128MB
    //   ball f32 [4096]         16KB
    //   kvg  f32 [64][64][64]    1MB
    //   ksg  f32 [64][64]       16KB
    char* W = (char*)d_ws;
    f16* xh   = (f16*)W;
    f16* q_ws = (f16*)(W + 33554432);
    f16* kT   = (f16*)(W + 67108864);
    f16* vT   = (f16*)(W + 100663296);
    f16* Wall = (f16*)(W + 134217728);
    float* ball = (float*)(W + 142606336);
    float* kvg  = (float*)(W + 142622720);
    float* ksg  = (float*)(W + 143671296);

    cvt_x<<<16384, 256, 0, stream>>>(x, xh);
    pack_w<<<4096, 256, 0, stream>>>(Wq, Wk, Wv, Wc, bq, bk, bv, bc, Wall, ball);

    const int nzero = BH * HD * HD + BH * HD;
    zero_kernel<<<(nzero + 255) / 256, 256, 0, stream>>>(kvg, nzero);

    gemm_qkv<<<dim3(128, 24), 256, 0, stream>>>(xh, Wall, ball, q_ws, kT, vT);

    kv_ksum<<<dim3(BH, 8), 256, 0, stream>>>(kT, vT, kvg, ksg);

    y_kernel<<<dim3(BH, TSEQ / 128), 256, 0, stream>>>(q_ws, kvg, ksg, q_ws);

    gemm_out<<<dim3(128, 8), 256, 0, stream>>>(q_ws, Wall, ball, out);
}

// Round 5
// 236.899 us; speedup vs baseline: 7.7435x; 1.0964x over previous
//
#include <hip/hip_runtime.h>
#include <math.h>

#define EMBED 1024
#define HEADS 16
#define HD 64
#define BATCH 4
#define TSEQ 4096
#define BH (BATCH * HEADS)
#define MROWS (BATCH * TSEQ)   // 16384

typedef _Float16 f16;
typedef __attribute__((ext_vector_type(4))) _Float16 f16x4;
typedef __attribute__((ext_vector_type(8))) _Float16 f16x8;
typedef __attribute__((ext_vector_type(4))) float f32x4;

#define GLOBAL_AS __attribute__((address_space(1)))
#define LDS_AS __attribute__((address_space(3)))

__device__ __forceinline__ float elu1(float v) {
    return v > 0.f ? v + 1.f : __expf(v);
}

// XOR-swizzled element offset in a [rows][cols] f16 tile; 16B granules.
__device__ __forceinline__ int swzc(int row, int col, int cols) {
    int g = (col >> 3) ^ (row & 7);
    return row * cols + (g << 3) + (col & 7);
}

__device__ __forceinline__ f16x8 fragld(const f16* t, int row, int k, int cols) {
    return *(const f16x8*)&t[swzc(row, k, cols)];
}

__device__ __forceinline__ f32x4 mfma16(f16x8 a, f16x8 b, f32x4 c) {
    return __builtin_amdgcn_mfma_f32_16x16x32_f16(a, b, c, 0, 0, 0);
}

// async global->LDS, 16B per lane. lds dest must be wave-uniform base.
__device__ __forceinline__ void gld_lds16(const f16* g, f16* l) {
    __builtin_amdgcn_global_load_lds((const GLOBAL_AS void*)g, (LDS_AS void*)l, 16, 0, 0);
}

__global__ __launch_bounds__(256) void zero_kernel(float* __restrict__ p, int n) {
    int i = blockIdx.x * 256 + threadIdx.x;
    if (i < n) p[i] = 0.f;
}

// x fp32 -> f16
__global__ __launch_bounds__(256) void cvt_x(const float* __restrict__ x, f16* __restrict__ xh) {
    size_t i4 = (size_t)blockIdx.x * 256 + threadIdx.x;
    float4 f = *(const float4*)&x[i4 * 4];
    f16x4 h = {(f16)f.x, (f16)f.y, (f16)f.z, (f16)f.w};
    *(f16x4*)&xh[i4 * 4] = h;
}

// pack [Wq;Wk;Wv;Wc] -> Wall f16 [4096][1024], biases -> ball f32 [4096]
__global__ __launch_bounds__(256) void pack_w(
    const float* __restrict__ Wq, const float* __restrict__ Wk,
    const float* __restrict__ Wv, const float* __restrict__ Wc,
    const float* __restrict__ bq, const float* __restrict__ bk,
    const float* __restrict__ bv, const float* __restrict__ bc,
    f16* __restrict__ Wall, float* __restrict__ ball)
{
    int i4 = blockIdx.x * 256 + threadIdx.x;           // < 1048576
    int cls = i4 >> 18;
    const float* W = cls == 0 ? Wq : cls == 1 ? Wk : cls == 2 ? Wv : Wc;
    int off = (i4 & 0x3FFFF) * 4;
    float4 f = *(const float4*)&W[off];
    f16x4 h = {(f16)f.x, (f16)f.y, (f16)f.z, (f16)f.w};
    *(f16x4*)&Wall[(size_t)i4 * 4] = h;
    if (i4 < 4096) {
        int c2 = i4 >> 10;
        const float* bb = c2 == 0 ? bq : c2 == 1 ? bk : c2 == 2 ? bv : bc;
        ball[i4] = bb[i4 & 1023];
    }
}

// ---------------------------------------------------------------------------
// gemm_qkv: C[16384, 3072] = xh @ Wall[0:3072]^T, f16 MFMA, fp32 acc.
// 128x128 tile, BK=64, 256 thr. Staging via global_load_lds (linear LDS dest,
// inverse-swizzled global source so swizzled ds_read fragments are unchanged).
// ---------------------------------------------------------------------------
__global__ __launch_bounds__(256) void gemm_qkv(
    const f16* __restrict__ xh, const f16* __restrict__ Wall,
    const float* __restrict__ ball,
    f16* __restrict__ q, f16* __restrict__ kT, f16* __restrict__ vT)
{
    __shared__ __align__(16) f16 As[128 * 64];
    __shared__ __align__(16) f16 Bs[128 * 64];

    const int tid = threadIdx.x, lane = tid & 63, w = tid >> 6;
    const int wr = w >> 1, wc4 = w & 1, l15 = lane & 15, l4 = lane >> 4;
    const int m0 = blockIdx.x * 128;
    const int n0 = blockIdx.y * 128;
    const int cls = n0 >> 10;

    // inverse-swizzled source column (elems) + row-within-chunk, lane-only
    const int gcol = ((lane & 7) ^ (lane >> 3)) << 3;
    const int rsub = lane >> 3;
    const size_t arow = (size_t)(m0 + w * 32 + rsub) * EMBED + gcol;
    const size_t brow = (size_t)(n0 + w * 32 + rsub) * EMBED + gcol;

    f32x4 acc[4][4];
    #pragma unroll
    for (int i = 0; i < 4; ++i)
        #pragma unroll
        for (int j = 0; j < 4; ++j) acc[i][j] = (f32x4){0.f, 0.f, 0.f, 0.f};

    for (int k0 = 0; k0 < EMBED; k0 += 64) {
        #pragma unroll
        for (int c = 0; c < 4; ++c) {
            gld_lds16(&xh[arow + (size_t)c * 8 * EMBED + k0], &As[(w * 4 + c) * 512]);
            gld_lds16(&Wall[brow + (size_t)c * 8 * EMBED + k0], &Bs[(w * 4 + c) * 512]);
        }
        __syncthreads();
        #pragma unroll
        for (int kk = 0; kk < 64; kk += 32) {
            f16x8 af[4], bf[4];
            #pragma unroll
            for (int i = 0; i < 4; ++i)
                af[i] = fragld(As, wr * 64 + i * 16 + l15, kk + l4 * 8, 64);
            #pragma unroll
            for (int j = 0; j < 4; ++j)
                bf[j] = fragld(Bs, wc4 * 64 + j * 16 + l15, kk + l4 * 8, 64);
            #pragma unroll
            for (int i = 0; i < 4; ++i)
                #pragma unroll
                for (int j = 0; j < 4; ++j)
                    acc[i][j] = mfma16(af[i], bf[j], acc[i][j]);
        }
        __syncthreads();
    }

    if (cls == 0) {
        #pragma unroll
        for (int j = 0; j < 4; ++j) {
            int c = n0 + wc4 * 64 + j * 16 + l15;
            float bj = ball[c];
            #pragma unroll
            for (int i = 0; i < 4; ++i) {
                #pragma unroll
                for (int r = 0; r < 4; ++r) {
                    int t = m0 + wr * 64 + i * 16 + l4 * 4 + r;
                    q[(size_t)t * EMBED + c] = (f16)elu1(acc[i][j][r] + bj);
                }
            }
        }
    } else {
        f16* dst = (cls == 1) ? kT : vT;
        const bool act = (cls == 1);
        #pragma unroll
        for (int j = 0; j < 4; ++j) {
            int n = n0 + wc4 * 64 + j * 16 + l15;
            int d = n & 1023;
            float bj = ball[n];
            #pragma unroll
            for (int i = 0; i < 4; ++i) {
                int t = m0 + wr * 64 + i * 16 + l4 * 4;
                f16x4 hv;
                #pragma unroll
                for (int r = 0; r < 4; ++r) {
                    float v = acc[i][j][r] + bj;
                    if (act) v = elu1(v);
                    hv[r] = (f16)v;
                }
                *(f16x4*)&dst[(size_t)d * MROWS + t] = hv;
            }
        }
    }
}

// ---------------------------------------------------------------------------
// kv_ksum: per (bh, 512-t chunk): kvg[e][d] += sum_t v[t,e] k[t,d] (MFMA),
// ksg[d] += sum_t k[t,d]. Inputs kT,vT are [1024 d][16384 t] f16.
// ---------------------------------------------------------------------------
__global__ __launch_bounds__(256) void kv_ksum(
    const f16* __restrict__ kT, const f16* __restrict__ vT,
    float* __restrict__ kvg, float* __restrict__ ksg)
{
    __shared__ __align__(16) f16 kl[64 * 128];
    __shared__ __align__(16) f16 vl[64 * 128];

    const int bh = blockIdx.x, b = bh >> 4, h = bh & 15;
    const int tid = threadIdx.x, lane = tid & 63, w = tid >> 6;
    const int l15 = lane & 15, l4 = lane >> 4;
    const int tbase = b * TSEQ + blockIdx.y * 512;

    f32x4 kvacc[4];
    #pragma unroll
    for (int j = 0; j < 4; ++j) kvacc[j] = (f32x4){0.f, 0.f, 0.f, 0.f};
    float ksacc = 0.f;

    for (int ss = 0; ss < 4; ++ss) {
        const int tg = tbase + ss * 128;
        #pragma unroll
        for (int c = 0; c < 4; ++c) {
            int idx = tid + c * 256;
            int row = idx >> 4, t8 = (idx & 15) << 3;
            f16x8 a = *(const f16x8*)&kT[(size_t)(h * 64 + row) * MROWS + tg + t8];
            *(f16x8*)&kl[swzc(row, t8, 128)] = a;
            f16x8 bb = *(const f16x8*)&vT[(size_t)(h * 64 + row) * MROWS + tg + t8];
            *(f16x8*)&vl[swzc(row, t8, 128)] = bb;
        }
        __syncthreads();
        #pragma unroll
        for (int kk = 0; kk < 128; kk += 32) {
            f16x8 a = fragld(vl, 16 * w + l15, kk + l4 * 8, 128);
            #pragma unroll
            for (int j = 0; j < 4; ++j) {
                f16x8 bfr = fragld(kl, j * 16 + l15, kk + l4 * 8, 128);
                kvacc[j] = mfma16(a, bfr, kvacc[j]);
            }
        }
        {
            int d = tid & 63, qq = tid >> 6;
            #pragma unroll
            for (int t8 = 0; t8 < 32; t8 += 8) {
                f16x8 kv8 = fragld(kl, d, qq * 32 + t8, 128);
                #pragma unroll
                for (int e = 0; e < 8; ++e) ksacc += (float)kv8[e];
            }
        }
        __syncthreads();
    }

    #pragma unroll
    for (int j = 0; j < 4; ++j)
        #pragma unroll
        for (int r = 0; r < 4; ++r)
            atomicAdd(&kvg[(size_t)bh * 4096 +
                           (size_t)(16 * w + l4 * 4 + r) * HD + j * 16 + l15],
                      kvacc[j][r]);
    atomicAdd(&ksg[bh * HD + (tid & 63)], ksacc);
}

// ---------------------------------------------------------------------------
// y_kernel: per (bh, 128 t): z[t]=1/(q.ks+1e-6); y[t][e]=sum_d q[t,d]kv[d,e]*z
// ---------------------------------------------------------------------------
__global__ __launch_bounds__(256) void y_kernel(
    const f16* __restrict__ q, const float* __restrict__ kvg,
    const float* __restrict__ ksg, f16* __restrict__ y)
{
    __shared__ __align__(16) f16 qs[128 * 64];
    __shared__ __align__(16) f16 kvs[64 * 64];
    __shared__ __align__(16) f16 ylds[128 * 64];
    __shared__ float kss[64];
    __shared__ float zs[128];

    const int bh = blockIdx.x, b = bh >> 4, h = bh & 15;
    const int tid = threadIdx.x, lane = tid & 63, w = tid >> 6;
    const int l15 = lane & 15, l4 = lane >> 4;
    const int t0g = b * TSEQ + blockIdx.y * 128;

    #pragma unroll
    for (int c = 0; c < 4; ++c) {
        int idx = tid + c * 256;
        int row = idx >> 3, col8 = (idx & 7) << 3;
        f16x8 v = *(const f16x8*)&q[(size_t)(t0g + row) * EMBED + h * 64 + col8];
        *(f16x8*)&qs[swzc(row, col8, 64)] = v;
    }
    #pragma unroll
    for (int c = 0; c < 4; ++c) {
        int idx = tid + c * 256;
        int e = idx >> 4, d4 = (idx & 15) << 2;
        float4 f = *(const float4*)&kvg[(size_t)bh * 4096 + e * 64 + d4];
        f16x4 hv = {(f16)f.x, (f16)f.y, (f16)f.z, (f16)f.w};
        *(f16x4*)&kvs[swzc(e, d4, 64)] = hv;
    }
    if (tid < 64) kss[tid] = ksg[bh * HD + tid];
    __syncthreads();

    {
        int t = tid >> 1, dh = (tid & 1) * 32;
        float s = 0.f;
        #pragma unroll
        for (int d8 = 0; d8 < 32; d8 += 8) {
            f16x8 qv = fragld(qs, t, dh + d8, 64);
            #pragma unroll
            for (int e = 0; e < 8; ++e) s += (float)qv[e] * kss[dh + d8 + e];
        }
        s += __shfl_xor(s, 1);
        if ((tid & 1) == 0) zs[t] = 1.f / (s + 1e-6f);
    }
    __syncthreads();

    f32x4 yacc[8];
    #pragma unroll
    for (int jn = 0; jn < 8; ++jn) yacc[jn] = (f32x4){0.f, 0.f, 0.f, 0.f};
    #pragma unroll
    for (int kk = 0; kk < 64; kk += 32) {
        f16x8 a = fragld(kvs, 16 * w + l15, kk + l4 * 8, 64);
        #pragma unroll
        for (int jn = 0; jn < 8; ++jn) {
            f16x8 bq8 = fragld(qs, jn * 16 + l15, kk + l4 * 8, 64);
            yacc[jn] = mfma16(a, bq8, yacc[jn]);
        }
    }
    #pragma unroll
    for (int jn = 0; jn < 8; ++jn) {
        int t = jn * 16 + l15;
        float z = zs[t];
        int e0 = 16 * w + l4 * 4;
        f16x4 hv;
        #pragma unroll
        for (int r = 0; r < 4; ++r) hv[r] = (f16)(yacc[jn][r] * z);
        *(f16x4*)&ylds[swzc(t, e0, 64)] = hv;
    }
    __syncthreads();

    {
        int row = tid >> 1, eh = (tid & 1) * 32;
        size_t gb = (size_t)(t0g + row) * EMBED + h * 64 + eh;
        #pragma unroll
        for (int c8 = 0; c8 < 32; c8 += 8) {
            f16x8 v = fragld(ylds, row, eh + c8, 64);
            *(f16x8*)&y[gb + c8] = v;
        }
    }
}

// ---------------------------------------------------------------------------
// gemm_out: out[M,1024] = y @ Wc^T + bc (Wc = Wall rows 3072..4095), fp32 out
// ---------------------------------------------------------------------------
__global__ __launch_bounds__(256) void gemm_out(
    const f16* __restrict__ y, const f16* __restrict__ Wall,
    const float* __restrict__ ball, float* __restrict__ out)
{
    __shared__ __align__(16) f16 As[128 * 64];
    __shared__ __align__(16) f16 Bs[128 * 64];

    const int tid = threadIdx.x, lane = tid & 63, w = tid >> 6;
    const int wr = w >> 1, wc4 = w & 1, l15 = lane & 15, l4 = lane >> 4;
    const int m0 = blockIdx.x * 128;
    const int n0 = blockIdx.y * 128;

    const int gcol = ((lane & 7) ^ (lane >> 3)) << 3;
    const int rsub = lane >> 3;
    const size_t arow = (size_t)(m0 + w * 32 + rsub) * EMBED + gcol;
    const size_t brow = (size_t)(3072 + n0 + w * 32 + rsub) * EMBED + gcol;

    f32x4 acc[4][4];
    #pragma unroll
    for (int i = 0; i < 4; ++i)
        #pragma unroll
        for (int j = 0; j < 4; ++j) acc[i][j] = (f32x4){0.f, 0.f, 0.f, 0.f};

    for (int k0 = 0; k0 < EMBED; k0 += 64) {
        #pragma unroll
        for (int c = 0; c < 4; ++c) {
            gld_lds16(&y[arow + (size_t)c * 8 * EMBED + k0], &As[(w * 4 + c) * 512]);
            gld_lds16(&Wall[brow + (size_t)c * 8 * EMBED + k0], &Bs[(w * 4 + c) * 512]);
        }
        __syncthreads();
        #pragma unroll
        for (int kk = 0; kk < 64; kk += 32) {
            f16x8 af[4], bf[4];
            #pragma unroll
            for (int i = 0; i < 4; ++i)
                af[i] = fragld(As, wr * 64 + i * 16 + l15, kk + l4 * 8, 64);
            #pragma unroll
            for (int j = 0; j < 4; ++j)
                bf[j] = fragld(Bs, wc4 * 64 + j * 16 + l15, kk + l4 * 8, 64);
            #pragma unroll
            for (int i = 0; i < 4; ++i)
                #pragma unroll
                for (int j = 0; j < 4; ++j)
                    acc[i][j] = mfma16(af[i], bf[j], acc[i][j]);
        }
        __syncthreads();
    }

    #pragma unroll
    for (int j = 0; j < 4; ++j) {
        int n = n0 + wc4 * 64 + j * 16 + l15;
        float bj = ball[3072 + n];
        #pragma unroll
        for (int i = 0; i < 4; ++i) {
            #pragma unroll
            for (int r = 0; r < 4; ++r) {
                int m = m0 + wr * 64 + i * 16 + l4 * 4 + r;
                out[(size_t)m * EMBED + n] = acc[i][j][r] + bj;
            }
        }
    }
}

// ---------------------------------------------------------------------------
extern "C" void kernel_launch(void* const* d_in, const int* in_sizes, int n_in,
                              void* d_out, int out_size, void* d_ws, size_t ws_size,
                              hipStream_t stream) {
    (void)in_sizes; (void)n_in; (void)out_size; (void)ws_size;
    const float* x  = (const float*)d_in[0];
    const float* Wq = (const float*)d_in[1];
    const float* bq = (const float*)d_in[2];
    const float* Wk = (const float*)d_in[3];
    const float* bk = (const float*)d_in[4];
    const float* Wv = (const float*)d_in[5];
    const float* bv = (const float*)d_in[6];
    const float* Wc = (const float*)d_in[7];
    const float* bc = (const float*)d_in[8];
    float* out = (float*)d_out;

    char* W = (char*)d_ws;
    f16* xh   = (f16*)W;
    f16* q_ws = (f16*)(W + 33554432);
    f16* kT   = (f16*)(W + 67108864);
    f16* vT   = (f16*)(W + 100663296);
    f16* Wall = (f16*)(W + 134217728);
    float* ball = (float*)(W + 142606336);
    float* kvg  = (float*)(W + 142622720);
    float* ksg  = (float*)(W + 143671296);

    cvt_x<<<16384, 256, 0, stream>>>(x, xh);
    pack_w<<<4096, 256, 0, stream>>>(Wq, Wk, Wv, Wc, bq, bk, bv, bc, Wall, ball);

    const int nzero = BH * HD * HD + BH * HD;
    zero_kernel<<<(nzero + 255) / 256, 256, 0, stream>>>(kvg, nzero);

    gemm_qkv<<<dim3(128, 24), 256, 0, stream>>>(xh, Wall, ball, q_ws, kT, vT);

    kv_ksum<<<dim3(BH, 8), 256, 0, stream>>>(kT, vT, kvg, ksg);

    y_kernel<<<dim3(BH, TSEQ / 128), 256, 0, stream>>>(q_ws, kvg, ksg, q_ws);

    gemm_out<<<dim3(128, 8), 256, 0, stream>>>(q_ws, Wall, ball, out);
}